// Round 1
// baseline (6216.041 us; speedup 1.0000x reference)
//
#include <hip/hip_runtime.h>
#include <math.h>

#define NN 100000
#define NE 3200000
#define FIN 256
#define HH 128
#define CC 64
#define NL 16

// ---------------- CSR build ----------------

__global__ void hist_kernel(const int* __restrict__ edst, int* __restrict__ counts) {
    int e = blockIdx.x * blockDim.x + threadIdx.x;
    if (e < NE) atomicAdd(&counts[edst[e]], 1);
}

__global__ void scan_kernel(const int* __restrict__ counts, int* __restrict__ row_start) {
    __shared__ int sums[1024];
    int tid = threadIdx.x;
    const int chunk = (NN + 1023) / 1024;  // 98
    int begin = tid * chunk;
    int end = begin + chunk; if (end > NN) end = NN;
    int s = 0;
    for (int i = begin; i < end; ++i) s += counts[i];
    sums[tid] = s;
    __syncthreads();
    for (int off = 1; off < 1024; off <<= 1) {
        int v = (tid >= off) ? sums[tid - off] : 0;
        __syncthreads();
        sums[tid] += v;
        __syncthreads();
    }
    int run = (tid == 0) ? 0 : sums[tid - 1];
    for (int i = begin; i < end; ++i) { row_start[i] = run; run += counts[i]; }
    if (tid == 1023) row_start[NN] = run;
}

__global__ void scatter_kernel(const int* __restrict__ esrc, const int* __restrict__ edst,
                               const float* __restrict__ ew, const int* __restrict__ row_start,
                               int* __restrict__ cursor, int* __restrict__ csr_src,
                               float* __restrict__ csr_w) {
    int e = blockIdx.x * blockDim.x + threadIdx.x;
    if (e < NE) {
        int d = edst[e];
        int pos = row_start[d] + atomicAdd(&cursor[d], 1);
        csr_src[pos] = esrc[e];
        csr_w[pos] = ew[e];
    }
}

// ---------------- lin0: x = relu(X @ W0 + b0), write to xcur and x0 ----------------
// block = 256 threads, 32 nodes/block. 4x4 register tile per thread.

__global__ __launch_bounds__(256) void lin0_kernel(const float* __restrict__ X,
                                                   const float* __restrict__ W0,
                                                   const float* __restrict__ B0,
                                                   float* __restrict__ xcur,
                                                   float* __restrict__ x0) {
    __shared__ float xs[32 * FIN];  // 32 KB
    __shared__ float ws[64 * HH];   // 32 KB
    int t = threadIdx.x;
    int nb = blockIdx.x * 32;
    for (int i = t; i < 32 * FIN; i += 256) {
        int node = nb + (i >> 8);
        xs[i] = (node < NN) ? X[(size_t)node * FIN + (i & 255)] : 0.f;
    }
    int tc = t & 31, tn = t >> 5;
    float acc[4][4] = {};
    for (int kc = 0; kc < 4; ++kc) {
        __syncthreads();
        for (int i = t; i < 64 * HH; i += 256) ws[i] = W0[kc * 64 * HH + i];
        __syncthreads();
        for (int k = 0; k < 64; ++k) {
            float wv[4], hv[4];
#pragma unroll
            for (int j = 0; j < 4; ++j) wv[j] = ws[k * HH + tc + 32 * j];
#pragma unroll
            for (int i = 0; i < 4; ++i) hv[i] = xs[(tn + 8 * i) * FIN + kc * 64 + k];
#pragma unroll
            for (int i = 0; i < 4; ++i)
#pragma unroll
                for (int j = 0; j < 4; ++j) acc[i][j] += hv[i] * wv[j];
        }
    }
#pragma unroll
    for (int i = 0; i < 4; ++i) {
        int node = nb + tn + 8 * i;
        if (node < NN) {
#pragma unroll
            for (int j = 0; j < 4; ++j) {
                int c = tc + 32 * j;
                float v = fmaxf(acc[i][j] + B0[c], 0.f);
                xcur[node * HH + c] = v;
                x0[node * HH + c] = v;
            }
        }
    }
}

// ---------------- SpMM + initial-residual mix: h = 0.9*agg + 0.1*x0 ----------------
// 2 nodes per 256-thread block; thread d of a node handles feature dim d.

__global__ __launch_bounds__(256) void spmm_kernel(const float* __restrict__ xcur,
                                                   const float* __restrict__ x0,
                                                   const int* __restrict__ csr_src,
                                                   const float* __restrict__ csr_w,
                                                   const int* __restrict__ row_start,
                                                   float* __restrict__ h) {
    int node = blockIdx.x * 2 + (threadIdx.x >> 7);
    int d = threadIdx.x & 127;
    if (node >= NN) return;
    int p = row_start[node], pe = row_start[node + 1];
    float acc = 0.f;
    for (; p + 4 <= pe; p += 4) {
        int s0 = csr_src[p], s1 = csr_src[p + 1], s2 = csr_src[p + 2], s3 = csr_src[p + 3];
        float w0 = csr_w[p], w1 = csr_w[p + 1], w2 = csr_w[p + 2], w3 = csr_w[p + 3];
        acc += w0 * xcur[s0 * HH + d];
        acc += w1 * xcur[s1 * HH + d];
        acc += w2 * xcur[s2 * HH + d];
        acc += w3 * xcur[s3 * HH + d];
    }
    for (; p < pe; ++p) acc += csr_w[p] * xcur[csr_src[p] * HH + d];
    int idx = node * HH + d;
    h[idx] = 0.9f * acc + 0.1f * x0[idx];
}

// ---------------- layer update: x = relu((1-b)*h + b*(h@W) + x) ----------------
// 64 nodes per block (2 chunks of 32), W in LDS (64 KB), 4x4 register tile.

__global__ __launch_bounds__(256) void layer_kernel(const float* __restrict__ h,
                                                    const float* __restrict__ W,
                                                    float* __restrict__ x, float beta) {
    __shared__ float wlds[HH * HH];  // 64 KB
    __shared__ float hs[32 * HH];    // 16 KB
    int t = threadIdx.x;
    for (int i = t; i < HH * HH; i += 256) wlds[i] = W[i];
    int tc = t & 31, tn = t >> 5;
    int nb0 = blockIdx.x * 64;
    for (int half = 0; half < 2; ++half) {
        int nb = nb0 + half * 32;
        __syncthreads();
        for (int i = t; i < 32 * HH; i += 256) {
            int node = nb + (i >> 7);
            hs[i] = (node < NN) ? h[node * HH + (i & 127)] : 0.f;
        }
        __syncthreads();
        float acc[4][4] = {};
        for (int k = 0; k < HH; ++k) {
            float wv[4], hv[4];
#pragma unroll
            for (int j = 0; j < 4; ++j) wv[j] = wlds[k * HH + tc + 32 * j];
#pragma unroll
            for (int i = 0; i < 4; ++i) hv[i] = hs[(tn + 8 * i) * HH + k];
#pragma unroll
            for (int i = 0; i < 4; ++i)
#pragma unroll
                for (int j = 0; j < 4; ++j) acc[i][j] += hv[i] * wv[j];
        }
#pragma unroll
        for (int i = 0; i < 4; ++i) {
            int node = nb + tn + 8 * i;
            if (node < NN) {
#pragma unroll
                for (int j = 0; j < 4; ++j) {
                    int c = tc + 32 * j;
                    float hval = hs[(tn + 8 * i) * HH + c];
                    float v = (1.f - beta) * hval + beta * acc[i][j];
                    float xv = x[node * HH + c];
                    x[node * HH + c] = fmaxf(v + xv, 0.f);
                }
            }
        }
    }
}

// ---------------- lin1: out = x @ W1 + b1 ----------------

__global__ __launch_bounds__(256) void lin1_kernel(const float* __restrict__ x,
                                                   const float* __restrict__ W1,
                                                   const float* __restrict__ B1,
                                                   float* __restrict__ out) {
    __shared__ float wlds[HH * CC];  // 32 KB
    __shared__ float hs[32 * 129];   // padded
    int t = threadIdx.x;
    for (int i = t; i < HH * CC; i += 256) wlds[i] = W1[i];
    int tc = t & 15, tn = t >> 4;
    int nb0 = blockIdx.x * 64;
    for (int half = 0; half < 2; ++half) {
        int nb = nb0 + half * 32;
        __syncthreads();
        for (int i = t; i < 32 * HH; i += 256) {
            int node = nb + (i >> 7);
            hs[(i >> 7) * 129 + (i & 127)] = (node < NN) ? x[node * HH + (i & 127)] : 0.f;
        }
        __syncthreads();
        float acc[2][4] = {};
        for (int k = 0; k < HH; ++k) {
            float wv[4], hv[2];
#pragma unroll
            for (int j = 0; j < 4; ++j) wv[j] = wlds[k * CC + tc + 16 * j];
#pragma unroll
            for (int i = 0; i < 2; ++i) hv[i] = hs[(tn + 16 * i) * 129 + k];
#pragma unroll
            for (int i = 0; i < 2; ++i)
#pragma unroll
                for (int j = 0; j < 4; ++j) acc[i][j] += hv[i] * wv[j];
        }
#pragma unroll
        for (int i = 0; i < 2; ++i) {
            int node = nb + tn + 16 * i;
            if (node < NN) {
#pragma unroll
                for (int j = 0; j < 4; ++j) {
                    int c = tc + 16 * j;
                    out[node * CC + c] = acc[i][j] + B1[c];
                }
            }
        }
    }
}

// ---------------- host ----------------

extern "C" void kernel_launch(void* const* d_in, const int* in_sizes, int n_in,
                              void* d_out, int out_size, void* d_ws, size_t ws_size,
                              hipStream_t stream) {
    const float* X  = (const float*)d_in[0];
    const int* esrc = (const int*)d_in[1];
    const int* edst = (const int*)d_in[2];
    const float* ew = (const float*)d_in[3];
    const float* W0 = (const float*)d_in[4];
    const float* B0 = (const float*)d_in[5];
    const float* W1 = (const float*)d_in[6];
    const float* B1 = (const float*)d_in[7];
    const float* CW = (const float*)d_in[8];
    float* out = (float*)d_out;

    char* p = (char*)d_ws;
    auto alloc = [&](size_t bytes) {
        char* r = p;
        p += (bytes + 255) & ~(size_t)255;
        return r;
    };
    float* xcur     = (float*)alloc((size_t)NN * HH * 4);
    float* x0       = (float*)alloc((size_t)NN * HH * 4);
    float* hbuf     = (float*)alloc((size_t)NN * HH * 4);
    int*   row_start= (int*)alloc((size_t)(NN + 1) * 4);
    int*   cursor   = (int*)alloc((size_t)NN * 4);
    int*   csr_src  = (int*)alloc((size_t)NE * 4);
    float* csr_w    = (float*)alloc((size_t)NE * 4);

    // CSR build (cursor doubles as the histogram buffer)
    hipMemsetAsync(cursor, 0, (size_t)NN * 4, stream);
    hist_kernel<<<NE / 256, 256, 0, stream>>>(edst, cursor);
    scan_kernel<<<1, 1024, 0, stream>>>(cursor, row_start);
    hipMemsetAsync(cursor, 0, (size_t)NN * 4, stream);
    scatter_kernel<<<NE / 256, 256, 0, stream>>>(esrc, edst, ew, row_start, cursor, csr_src, csr_w);

    lin0_kernel<<<(NN + 31) / 32, 256, 0, stream>>>(X, W0, B0, xcur, x0);

    for (int l = 0; l < NL; ++l) {
        float beta = (float)log(0.5 / (double)(l + 1) + 1.0);
        spmm_kernel<<<NN / 2, 256, 0, stream>>>(xcur, x0, csr_src, csr_w, row_start, hbuf);
        layer_kernel<<<(NN + 63) / 64, 256, 0, stream>>>(hbuf, CW + (size_t)l * HH * HH, xcur, beta);
    }

    lin1_kernel<<<(NN + 63) / 64, 256, 0, stream>>>(xcur, W1, B1, out);
}

// Round 2
// 3833.027 us; speedup vs baseline: 1.6217x; 1.6217x over previous
//
#include <hip/hip_runtime.h>
#include <math.h>

#define NN 100000
#define NE 3200000
#define FIN 256
#define HH 128
#define CC 64
#define NL 16

typedef unsigned short u16;
typedef unsigned int u32;

__device__ __forceinline__ float bf2f(u16 u) {
    u32 v = ((u32)u) << 16;
    return __builtin_bit_cast(float, v);
}
__device__ __forceinline__ u16 f2bf(float f) {
    u32 x = __builtin_bit_cast(u32, f);
    u32 lsb = (x >> 16) & 1;
    x += 0x7fffu + lsb;
    return (u16)(x >> 16);
}
__device__ __forceinline__ u32 pack2(float a, float b) {
    return (u32)f2bf(a) | ((u32)f2bf(b) << 16);
}

// ---------------- CSR build ----------------

__global__ void hist_kernel(const int* __restrict__ edst, int* __restrict__ counts) {
    int e = blockIdx.x * blockDim.x + threadIdx.x;
    if (e < NE) atomicAdd(&counts[edst[e]], 1);
}

__global__ void scan_kernel(const int* __restrict__ counts, int* __restrict__ row_start) {
    __shared__ int sums[1024];
    int tid = threadIdx.x;
    const int chunk = (NN + 1023) / 1024;  // 98
    int begin = tid * chunk;
    int end = begin + chunk; if (end > NN) end = NN;
    int s = 0;
    for (int i = begin; i < end; ++i) s += counts[i];
    sums[tid] = s;
    __syncthreads();
    for (int off = 1; off < 1024; off <<= 1) {
        int v = (tid >= off) ? sums[tid - off] : 0;
        __syncthreads();
        sums[tid] += v;
        __syncthreads();
    }
    int run = (tid == 0) ? 0 : sums[tid - 1];
    for (int i = begin; i < end; ++i) { row_start[i] = run; run += counts[i]; }
    if (tid == 1023) row_start[NN] = run;
}

__global__ void scatter_kernel(const int* __restrict__ esrc, const int* __restrict__ edst,
                               const float* __restrict__ ew, const int* __restrict__ row_start,
                               int* __restrict__ cursor, int* __restrict__ csr_src,
                               float* __restrict__ csr_w) {
    int e = blockIdx.x * blockDim.x + threadIdx.x;
    if (e < NE) {
        int d = edst[e];
        int pos = row_start[d] + atomicAdd(&cursor[d], 1);
        csr_src[pos] = esrc[e];
        csr_w[pos] = ew[e];
    }
}

// ---------------- lin0: x = relu(X @ W0 + b0) -> xcur (bf16) and x0 (bf16) ----------------

__global__ __launch_bounds__(256) void lin0_kernel(const float* __restrict__ X,
                                                   const float* __restrict__ W0,
                                                   const float* __restrict__ B0,
                                                   u32* __restrict__ xcur,
                                                   u32* __restrict__ x0) {
    __shared__ float xs[32 * FIN];  // 32 KB
    __shared__ float ws[64 * HH];   // 32 KB
    int t = threadIdx.x;
    int nb = blockIdx.x * 32;
    for (int i = t; i < 32 * FIN; i += 256) {
        int node = nb + (i >> 8);
        xs[i] = (node < NN) ? X[(size_t)node * FIN + (i & 255)] : 0.f;
    }
    int tc = t & 31, tn = t >> 5;
    float acc[4][4] = {};
    for (int kc = 0; kc < 4; ++kc) {
        __syncthreads();
        for (int i = t; i < 64 * HH; i += 256) ws[i] = W0[kc * 64 * HH + i];
        __syncthreads();
        for (int k = 0; k < 64; ++k) {
            float wv[4], hv[4];
#pragma unroll
            for (int j = 0; j < 4; ++j) wv[j] = ws[k * HH + 2 * tc + (j & 1) + 64 * (j >> 1)];
#pragma unroll
            for (int i = 0; i < 4; ++i) hv[i] = xs[(tn + 8 * i) * FIN + kc * 64 + k];
#pragma unroll
            for (int i = 0; i < 4; ++i)
#pragma unroll
                for (int j = 0; j < 4; ++j) acc[i][j] += hv[i] * wv[j];
        }
    }
#pragma unroll
    for (int i = 0; i < 4; ++i) {
        int node = nb + tn + 8 * i;
        if (node < NN) {
#pragma unroll
            for (int jj = 0; jj < 2; ++jj) {
                int c0 = 2 * tc + 64 * jj;
                float v0 = fmaxf(acc[i][2 * jj] + B0[c0], 0.f);
                float v1 = fmaxf(acc[i][2 * jj + 1] + B0[c0 + 1], 0.f);
                u32 pk = pack2(v0, v1);
                xcur[node * 64 + tc + 32 * jj] = pk;
                x0[node * 64 + tc + 32 * jj] = pk;
            }
        }
    }
}

// ---------------- SpMM + initial-residual mix: h = 0.9*agg + 0.1*x0 (all bf16) ----------------
// One wave (64 lanes) per node; each lane owns a bf16 pair (features 2d, 2d+1).

__global__ __launch_bounds__(256) void spmm_kernel(const u32* __restrict__ xcur,
                                                   const u32* __restrict__ x0,
                                                   const int* __restrict__ csr_src,
                                                   const float* __restrict__ csr_w,
                                                   const int* __restrict__ row_start,
                                                   u32* __restrict__ h) {
    int node = blockIdx.x * 4 + (threadIdx.x >> 6);
    int d2 = threadIdx.x & 63;
    if (node >= NN) return;
    int p = row_start[node], pe = row_start[node + 1];
    float acc0 = 0.f, acc1 = 0.f;
    for (; p + 4 <= pe; p += 4) {
        int s0 = csr_src[p], s1 = csr_src[p + 1], s2 = csr_src[p + 2], s3 = csr_src[p + 3];
        float w0 = csr_w[p], w1 = csr_w[p + 1], w2 = csr_w[p + 2], w3 = csr_w[p + 3];
        u32 v0 = xcur[s0 * 64 + d2];
        u32 v1 = xcur[s1 * 64 + d2];
        u32 v2 = xcur[s2 * 64 + d2];
        u32 v3 = xcur[s3 * 64 + d2];
        acc0 += w0 * bf2f((u16)v0); acc1 += w0 * bf2f((u16)(v0 >> 16));
        acc0 += w1 * bf2f((u16)v1); acc1 += w1 * bf2f((u16)(v1 >> 16));
        acc0 += w2 * bf2f((u16)v2); acc1 += w2 * bf2f((u16)(v2 >> 16));
        acc0 += w3 * bf2f((u16)v3); acc1 += w3 * bf2f((u16)(v3 >> 16));
    }
    for (; p < pe; ++p) {
        float w = csr_w[p];
        u32 v = xcur[csr_src[p] * 64 + d2];
        acc0 += w * bf2f((u16)v); acc1 += w * bf2f((u16)(v >> 16));
    }
    int idx = node * 64 + d2;
    u32 xv = x0[idx];
    float r0 = 0.9f * acc0 + 0.1f * bf2f((u16)xv);
    float r1 = 0.9f * acc1 + 0.1f * bf2f((u16)(xv >> 16));
    h[idx] = pack2(r0, r1);
}

// ---------------- layer update: x = relu((1-b)*h + b*(h@W) + x) ----------------
// 64 nodes per block (2 chunks of 32), W fp32 in LDS, h staged bf16->fp32 LDS.

__global__ __launch_bounds__(256) void layer_kernel(const u32* __restrict__ h,
                                                    const float* __restrict__ W,
                                                    u32* __restrict__ x, float beta) {
    __shared__ float wlds[HH * HH];  // 64 KB
    __shared__ float hs[32 * HH];    // 16 KB
    int t = threadIdx.x;
    for (int i = t; i < HH * HH; i += 256) wlds[i] = W[i];
    int tc = t & 31, tn = t >> 5;
    int nb0 = blockIdx.x * 64;
    for (int half = 0; half < 2; ++half) {
        int nb = nb0 + half * 32;
        __syncthreads();
        for (int i = t; i < 32 * 64; i += 256) {
            int node = nb + (i >> 6);
            u32 v = (node < NN) ? h[node * 64 + (i & 63)] : 0u;
            hs[(i >> 6) * HH + 2 * (i & 63)]     = bf2f((u16)v);
            hs[(i >> 6) * HH + 2 * (i & 63) + 1] = bf2f((u16)(v >> 16));
        }
        __syncthreads();
        float acc[4][4] = {};
        for (int k = 0; k < HH; ++k) {
            float wv[4], hv[4];
#pragma unroll
            for (int j = 0; j < 4; ++j) wv[j] = wlds[k * HH + 2 * tc + (j & 1) + 64 * (j >> 1)];
#pragma unroll
            for (int i = 0; i < 4; ++i) hv[i] = hs[(tn + 8 * i) * HH + k];
#pragma unroll
            for (int i = 0; i < 4; ++i)
#pragma unroll
                for (int j = 0; j < 4; ++j) acc[i][j] += hv[i] * wv[j];
        }
#pragma unroll
        for (int i = 0; i < 4; ++i) {
            int node = nb + tn + 8 * i;
            if (node < NN) {
#pragma unroll
                for (int jj = 0; jj < 2; ++jj) {
                    int c0 = 2 * tc + 64 * jj;
                    float h0 = hs[(tn + 8 * i) * HH + c0];
                    float h1 = hs[(tn + 8 * i) * HH + c0 + 1];
                    float v0 = (1.f - beta) * h0 + beta * acc[i][2 * jj];
                    float v1 = (1.f - beta) * h1 + beta * acc[i][2 * jj + 1];
                    u32 xv = x[node * 64 + tc + 32 * jj];
                    float r0 = fmaxf(v0 + bf2f((u16)xv), 0.f);
                    float r1 = fmaxf(v1 + bf2f((u16)(xv >> 16)), 0.f);
                    x[node * 64 + tc + 32 * jj] = pack2(r0, r1);
                }
            }
        }
    }
}

// ---------------- lin1: out = x @ W1 + b1 (out fp32) ----------------

__global__ __launch_bounds__(256) void lin1_kernel(const u32* __restrict__ x,
                                                   const float* __restrict__ W1,
                                                   const float* __restrict__ B1,
                                                   float* __restrict__ out) {
    __shared__ float wlds[HH * CC];  // 32 KB
    __shared__ float hs[32 * 129];
    int t = threadIdx.x;
    for (int i = t; i < HH * CC; i += 256) wlds[i] = W1[i];
    int tc = t & 15, tn = t >> 4;
    int nb0 = blockIdx.x * 64;
    for (int half = 0; half < 2; ++half) {
        int nb = nb0 + half * 32;
        __syncthreads();
        for (int i = t; i < 32 * 64; i += 256) {
            int node = nb + (i >> 6);
            u32 v = (node < NN) ? x[node * 64 + (i & 63)] : 0u;
            hs[(i >> 6) * 129 + 2 * (i & 63)]     = bf2f((u16)v);
            hs[(i >> 6) * 129 + 2 * (i & 63) + 1] = bf2f((u16)(v >> 16));
        }
        __syncthreads();
        float acc[2][4] = {};
        for (int k = 0; k < HH; ++k) {
            float wv[4], hv[2];
#pragma unroll
            for (int j = 0; j < 4; ++j) wv[j] = wlds[k * CC + tc + 16 * j];
#pragma unroll
            for (int i = 0; i < 2; ++i) hv[i] = hs[(tn + 16 * i) * 129 + k];
#pragma unroll
            for (int i = 0; i < 2; ++i)
#pragma unroll
                for (int j = 0; j < 4; ++j) acc[i][j] += hv[i] * wv[j];
        }
#pragma unroll
        for (int i = 0; i < 2; ++i) {
            int node = nb + tn + 16 * i;
            if (node < NN) {
#pragma unroll
                for (int j = 0; j < 4; ++j) {
                    int c = tc + 16 * j;
                    out[node * CC + c] = acc[i][j] + B1[c];
                }
            }
        }
    }
}

// ---------------- host ----------------

extern "C" void kernel_launch(void* const* d_in, const int* in_sizes, int n_in,
                              void* d_out, int out_size, void* d_ws, size_t ws_size,
                              hipStream_t stream) {
    const float* X  = (const float*)d_in[0];
    const int* esrc = (const int*)d_in[1];
    const int* edst = (const int*)d_in[2];
    const float* ew = (const float*)d_in[3];
    const float* W0 = (const float*)d_in[4];
    const float* B0 = (const float*)d_in[5];
    const float* W1 = (const float*)d_in[6];
    const float* B1 = (const float*)d_in[7];
    const float* CW = (const float*)d_in[8];
    float* out = (float*)d_out;

    char* p = (char*)d_ws;
    auto alloc = [&](size_t bytes) {
        char* r = p;
        p += (bytes + 255) & ~(size_t)255;
        return r;
    };
    u32*   xcur     = (u32*)alloc((size_t)NN * HH * 2);
    u32*   x0       = (u32*)alloc((size_t)NN * HH * 2);
    u32*   hbuf     = (u32*)alloc((size_t)NN * HH * 2);
    int*   row_start= (int*)alloc((size_t)(NN + 1) * 4);
    int*   cursor   = (int*)alloc((size_t)NN * 4);
    int*   csr_src  = (int*)alloc((size_t)NE * 4);
    float* csr_w    = (float*)alloc((size_t)NE * 4);

    // CSR build (cursor doubles as the histogram buffer)
    hipMemsetAsync(cursor, 0, (size_t)NN * 4, stream);
    hist_kernel<<<NE / 256, 256, 0, stream>>>(edst, cursor);
    scan_kernel<<<1, 1024, 0, stream>>>(cursor, row_start);
    hipMemsetAsync(cursor, 0, (size_t)NN * 4, stream);
    scatter_kernel<<<NE / 256, 256, 0, stream>>>(esrc, edst, ew, row_start, cursor, csr_src, csr_w);

    lin0_kernel<<<(NN + 31) / 32, 256, 0, stream>>>(X, W0, B0, xcur, x0);

    for (int l = 0; l < NL; ++l) {
        float beta = (float)log(0.5 / (double)(l + 1) + 1.0);
        spmm_kernel<<<(NN + 3) / 4, 256, 0, stream>>>(xcur, x0, csr_src, csr_w, row_start, hbuf);
        layer_kernel<<<(NN + 63) / 64, 256, 0, stream>>>(hbuf, CW + (size_t)l * HH * HH, xcur, beta);
    }

    lin1_kernel<<<(NN + 63) / 64, 256, 0, stream>>>(xcur, W1, B1, out);
}

// Round 3
// 2766.202 us; speedup vs baseline: 2.2471x; 1.3857x over previous
//
#include <hip/hip_runtime.h>
#include <math.h>

#define NN 100000
#define NE 3200000
#define FIN 256
#define HH 128
#define CC 64
#define NL 16

typedef unsigned short u16;
typedef unsigned int u32;
typedef short short8 __attribute__((ext_vector_type(8)));
typedef float f32x4 __attribute__((ext_vector_type(4)));
typedef float float8 __attribute__((ext_vector_type(8)));

__device__ __forceinline__ float bf2f(u16 u) {
    u32 v = ((u32)u) << 16;
    return __builtin_bit_cast(float, v);
}
__device__ __forceinline__ u16 f2bf(float f) {
    u32 x = __builtin_bit_cast(u32, f);
    u32 lsb = (x >> 16) & 1;
    x += 0x7fffu + lsb;
    return (u16)(x >> 16);
}
__device__ __forceinline__ u32 pack2(float a, float b) {
    return (u32)f2bf(a) | ((u32)f2bf(b) << 16);
}

// ---------------- CSR build ----------------

__global__ void hist_kernel(const int* __restrict__ edst, int* __restrict__ counts,
                            int* __restrict__ rank) {
    int e = blockIdx.x * blockDim.x + threadIdx.x;
    if (e < NE) rank[e] = atomicAdd(&counts[edst[e]], 1);
}

__global__ void scan_kernel(const int* __restrict__ counts, int* __restrict__ row_start) {
    __shared__ int sums[1024];
    int tid = threadIdx.x;
    const int chunk = (NN + 1023) / 1024;  // 98
    int begin = tid * chunk;
    int end = begin + chunk; if (end > NN) end = NN;
    int s = 0;
    for (int i = begin; i < end; ++i) s += counts[i];
    sums[tid] = s;
    __syncthreads();
    for (int off = 1; off < 1024; off <<= 1) {
        int v = (tid >= off) ? sums[tid - off] : 0;
        __syncthreads();
        sums[tid] += v;
        __syncthreads();
    }
    int run = (tid == 0) ? 0 : sums[tid - 1];
    for (int i = begin; i < end; ++i) { row_start[i] = run; run += counts[i]; }
    if (tid == 1023) row_start[NN] = run;
}

__global__ void scatter_kernel(const int* __restrict__ esrc, const int* __restrict__ edst,
                               const float* __restrict__ ew, const int* __restrict__ row_start,
                               const int* __restrict__ rank, int2* __restrict__ csr) {
    int e = blockIdx.x * blockDim.x + threadIdx.x;
    if (e < NE) {
        int d = edst[e];
        int pos = row_start[d] + rank[e];
        csr[pos] = make_int2(esrc[e], __builtin_bit_cast(int, ew[e]));
    }
}

// ---------------- weight fragment prep ----------------
// Fragment f of a weight set [K x N]: lane holds 8 contiguous bf16 =
// W[k0*32 + (lane>>4)*8 + i][j*16 + (lane&15)], stored at frag*512 + lane*8 + i.
// frag id within set = j*KB + k0 (KB = K/32). Layers store W' = (1-b)I + b*W.
// Global frag index: [0,64) lin0 (K=256,N=128); [64,576) layers; [576,592) lin1.

__global__ void prep_kernel(const float* __restrict__ W0, const float* __restrict__ W1,
                            const float* __restrict__ CW, u16* __restrict__ Wfrag) {
    int f = blockIdx.x;
    int lane = threadIdx.x;  // 64
    const float* Wsrc;
    int KB, N, fl;
    float beta = -1.f;
    if (f < 64) { Wsrc = W0; KB = 8; N = 128; fl = f; }
    else if (f < 576) {
        int l = (f - 64) >> 5; fl = (f - 64) & 31;
        Wsrc = CW + (size_t)l * HH * HH; KB = 4; N = 128;
        beta = logf(0.5f / (float)(l + 1) + 1.0f);
    } else { Wsrc = W1; KB = 4; N = 64; fl = f - 576; }
    int j = fl / KB, k0 = fl % KB;
    int n = j * 16 + (lane & 15);
    u16* dst = Wfrag + (size_t)f * 512 + lane * 8;
#pragma unroll
    for (int i = 0; i < 8; ++i) {
        int k = k0 * 32 + ((lane >> 4) << 3) + i;
        float v = Wsrc[(size_t)k * N + n];
        if (beta >= 0.f) v = beta * v + ((k == n) ? (1.f - beta) : 0.f);
        dst[i] = f2bf(v);
    }
}

// ---------------- lin0: x = relu(X @ W0 + b0) -> xcur, x0 (bf16) ----------------
// 4 waves/block, wave = 16 rows x 128 cols, MFMA 16x16x32, A from fp32 X (cvt in reg).

__global__ __launch_bounds__(256) void lin0_kernel(const float* __restrict__ X,
                                                   const u16* __restrict__ wf,
                                                   const float* __restrict__ B0,
                                                   u16* __restrict__ xcur,
                                                   u16* __restrict__ x0) {
    int lane = threadIdx.x & 63, w = threadIdx.x >> 6;
    int mb = (blockIdx.x * 4 + w) * 16;
    int r = lane & 15, g = lane >> 4;
    int arow = mb + r; if (arow >= NN) arow = NN - 1;
    const float* aprow = X + (size_t)arow * FIN + g * 8;
    const short8* bp = (const short8*)wf + lane;
    f32x4 acc[8] = {};
#pragma unroll
    for (int k0 = 0; k0 < 8; ++k0) {
        float8 af = *(const float8*)(aprow + k0 * 32);
        short8 a;
#pragma unroll
        for (int i = 0; i < 8; ++i) a[i] = (short)f2bf(af[i]);
#pragma unroll
        for (int j = 0; j < 8; ++j)
            acc[j] = __builtin_amdgcn_mfma_f32_16x16x32_bf16(a, bp[(j * 8 + k0) * 64], acc[j], 0, 0, 0);
    }
#pragma unroll
    for (int j = 0; j < 8; ++j) {
        int col = j * 16 + r;
        float b = B0[col];
#pragma unroll
        for (int reg = 0; reg < 4; ++reg) {
            int row = mb + g * 4 + reg;
            if (row < NN) {
                size_t idx = (size_t)row * HH + col;
                u16 v = f2bf(fmaxf(acc[j][reg] + b, 0.f));
                xcur[idx] = v;
                x0[idx] = v;
            }
        }
    }
}

// ---------------- SpMM + residual mix: h = 0.9*agg + 0.1*x0 ----------------
// One wave per node; lane owns bf16 feature pair (2*d2, 2*d2+1).

__global__ __launch_bounds__(256) void spmm_kernel(const u32* __restrict__ xcur,
                                                   const u32* __restrict__ x0,
                                                   const int2* __restrict__ csr,
                                                   const int* __restrict__ row_start,
                                                   u32* __restrict__ h) {
    int node = blockIdx.x * 4 + (threadIdx.x >> 6);
    int d2 = threadIdx.x & 63;
    if (node >= NN) return;
    int p = row_start[node], pe = row_start[node + 1];
    float acc0 = 0.f, acc1 = 0.f;
    for (; p + 8 <= pe; p += 8) {
        int2 m[8];
#pragma unroll
        for (int q = 0; q < 8; ++q) m[q] = csr[p + q];
        u32 v[8];
#pragma unroll
        for (int q = 0; q < 8; ++q) v[q] = xcur[(size_t)m[q].x * 64 + d2];
#pragma unroll
        for (int q = 0; q < 8; ++q) {
            float w = __builtin_bit_cast(float, m[q].y);
            acc0 += w * bf2f((u16)v[q]);
            acc1 += w * bf2f((u16)(v[q] >> 16));
        }
    }
    for (; p < pe; ++p) {
        int2 m = csr[p];
        float w = __builtin_bit_cast(float, m.y);
        u32 v = xcur[(size_t)m.x * 64 + d2];
        acc0 += w * bf2f((u16)v);
        acc1 += w * bf2f((u16)(v >> 16));
    }
    int idx = node * 64 + d2;
    u32 xv = x0[idx];
    float r0 = 0.9f * acc0 + 0.1f * bf2f((u16)xv);
    float r1 = 0.9f * acc1 + 0.1f * bf2f((u16)(xv >> 16));
    h[idx] = pack2(r0, r1);
}

// ---------------- layer: x = relu(h @ W' + x), W' = (1-b)I + b*W ----------------

__global__ __launch_bounds__(256) void layer_kernel(const u16* __restrict__ h,
                                                    const u16* __restrict__ wf,
                                                    u16* __restrict__ x) {
    int lane = threadIdx.x & 63, w = threadIdx.x >> 6;
    int mb = (blockIdx.x * 4 + w) * 16;
    int r = lane & 15, g = lane >> 4;
    int arow = mb + r; if (arow >= NN) arow = NN - 1;
    const short8* ap = (const short8*)(h + (size_t)arow * HH) + g;
    const short8* bp = (const short8*)wf + lane;
    f32x4 acc[8] = {};
#pragma unroll
    for (int k0 = 0; k0 < 4; ++k0) {
        short8 a = ap[k0 * 4];
#pragma unroll
        for (int j = 0; j < 8; ++j)
            acc[j] = __builtin_amdgcn_mfma_f32_16x16x32_bf16(a, bp[(j * 4 + k0) * 64], acc[j], 0, 0, 0);
    }
#pragma unroll
    for (int j = 0; j < 8; ++j) {
        int col = j * 16 + r;
#pragma unroll
        for (int reg = 0; reg < 4; ++reg) {
            int row = mb + g * 4 + reg;
            if (row < NN) {
                size_t idx = (size_t)row * HH + col;
                float v = acc[j][reg] + bf2f(x[idx]);
                x[idx] = f2bf(fmaxf(v, 0.f));
            }
        }
    }
}

// ---------------- lin1: out = x @ W1 + b1 (fp32 out) ----------------

__global__ __launch_bounds__(256) void lin1_kernel(const u16* __restrict__ x,
                                                   const u16* __restrict__ wf,
                                                   const float* __restrict__ B1,
                                                   float* __restrict__ out) {
    int lane = threadIdx.x & 63, w = threadIdx.x >> 6;
    int mb = (blockIdx.x * 4 + w) * 16;
    int r = lane & 15, g = lane >> 4;
    int arow = mb + r; if (arow >= NN) arow = NN - 1;
    const short8* ap = (const short8*)(x + (size_t)arow * HH) + g;
    const short8* bp = (const short8*)wf + lane;
    f32x4 acc[4] = {};
#pragma unroll
    for (int k0 = 0; k0 < 4; ++k0) {
        short8 a = ap[k0 * 4];
#pragma unroll
        for (int j = 0; j < 4; ++j)
            acc[j] = __builtin_amdgcn_mfma_f32_16x16x32_bf16(a, bp[(j * 4 + k0) * 64], acc[j], 0, 0, 0);
    }
#pragma unroll
    for (int j = 0; j < 4; ++j) {
        int col = j * 16 + r;
        float b = B1[col];
#pragma unroll
        for (int reg = 0; reg < 4; ++reg) {
            int row = mb + g * 4 + reg;
            if (row < NN) out[(size_t)row * CC + col] = acc[j][reg] + b;
        }
    }
}

// ---------------- host ----------------

extern "C" void kernel_launch(void* const* d_in, const int* in_sizes, int n_in,
                              void* d_out, int out_size, void* d_ws, size_t ws_size,
                              hipStream_t stream) {
    const float* X  = (const float*)d_in[0];
    const int* esrc = (const int*)d_in[1];
    const int* edst = (const int*)d_in[2];
    const float* ew = (const float*)d_in[3];
    const float* W0 = (const float*)d_in[4];
    const float* B0 = (const float*)d_in[5];
    const float* W1 = (const float*)d_in[6];
    const float* B1 = (const float*)d_in[7];
    const float* CW = (const float*)d_in[8];
    float* out = (float*)d_out;

    char* p = (char*)d_ws;
    auto alloc = [&](size_t bytes) {
        char* r = p;
        p += (bytes + 255) & ~(size_t)255;
        return r;
    };
    u16*  xcur      = (u16*)alloc((size_t)NN * HH * 2);
    u16*  x0        = (u16*)alloc((size_t)NN * HH * 2);
    u16*  hbuf      = (u16*)alloc((size_t)NN * HH * 2);
    int*  row_start = (int*)alloc((size_t)(NN + 1) * 4);
    int*  counts    = (int*)alloc((size_t)NN * 4);
    int*  rank      = (int*)alloc((size_t)NE * 4);
    int2* csr       = (int2*)alloc((size_t)NE * 8);
    u16*  Wfrag     = (u16*)alloc((size_t)592 * 512 * 2);

    hipMemsetAsync(counts, 0, (size_t)NN * 4, stream);
    hist_kernel<<<NE / 256, 256, 0, stream>>>(edst, counts, rank);
    scan_kernel<<<1, 1024, 0, stream>>>(counts, row_start);
    scatter_kernel<<<NE / 256, 256, 0, stream>>>(esrc, edst, ew, row_start, rank, csr);
    prep_kernel<<<592, 64, 0, stream>>>(W0, W1, CW, Wfrag);

    const int gemm_blocks = (NN + 63) / 64;
    lin0_kernel<<<gemm_blocks, 256, 0, stream>>>(X, Wfrag, B0, xcur, x0);

    for (int l = 0; l < NL; ++l) {
        spmm_kernel<<<(NN + 3) / 4, 256, 0, stream>>>((const u32*)xcur, (const u32*)x0,
                                                      csr, row_start, (u32*)hbuf);
        layer_kernel<<<gemm_blocks, 256, 0, stream>>>(hbuf, Wfrag + (size_t)(64 + 32 * l) * 512, xcur);
    }

    lin1_kernel<<<gemm_blocks, 256, 0, stream>>>(xcur, Wfrag + (size_t)576 * 512, B1, out);
}